// Round 2
// baseline (199.252 us; speedup 1.0000x reference)
//
#include <hip/hip_runtime.h>

typedef __bf16 bf16x8 __attribute__((ext_vector_type(8)));
typedef float f32x4 __attribute__((ext_vector_type(4)));
typedef unsigned short ushort8 __attribute__((ext_vector_type(8)));

#define BATCH 8
#define SEQ 4096
#define DH 128
#define PSTR 40
#define SC (0.08838834764831845f * 1.4426950408889634f)

// Dynamic-LDS map (u16 units):
//   K tiles : (kh*2+buf)*4096          [0     .. 16383]  32 rows x 128 u16, XOR-swizzled (byte ^= (row&7)<<4)
//   V tiles : OFF_V + (kh*2+buf)*4096  [16384 .. 32767]  128 d-rows x 32 u16; 16B slots XOR-swizzled by (row>>1)&3
//   P       : OFF_P + wv*1280          [32768 .. 37887]
#define OFF_V 16384
#define OFF_P 32768
#define SMEM_BYTES 75776   // 37888 u16 ; x2 blocks/CU = 151.5 KB <= 160 KB
#define LBUF_BYTE 36864    // epilogue l-buffer; Om region ends <= 36864

__device__ __forceinline__ unsigned short f2bf(float x) {
    unsigned int u = __builtin_bit_cast(unsigned int, x);
    u = (u + 0x7FFFu + ((u >> 16) & 1u)) >> 16;
    return (unsigned short)u;
}
__device__ __forceinline__ ushort8 cvt8(const float* __restrict__ p) {
    f32x4 a = *(const f32x4*)p;
    f32x4 b = *(const f32x4*)(p + 4);
    ushort8 r;
    r[0] = f2bf(a[0]); r[1] = f2bf(a[1]); r[2] = f2bf(a[2]); r[3] = f2bf(a[3]);
    r[4] = f2bf(b[0]); r[5] = f2bf(b[1]); r[6] = f2bf(b[2]); r[7] = f2bf(b[3]);
    return r;
}
__device__ __forceinline__ bf16x8 ldb(const unsigned short* p) {
    return __builtin_bit_cast(bf16x8, *(const ushort8*)p);
}
__device__ __forceinline__ void gll16(const void* src, void* dst) {
    // direct global->LDS, 16B per lane; LDS dest = wave-uniform base + lane*16
    __builtin_amdgcn_global_load_lds((const __attribute__((address_space(1))) unsigned int*)src,
                                     (__attribute__((address_space(3))) unsigned int*)dst, 16, 0, 0);
}

// ---------------- merged prep kernel (1 launch): K->bf16, V->bf16 transposed ----------------
__global__ __launch_bounds__(256) void prep_all(const float* __restrict__ Kg,
                                                const float* __restrict__ Vg,
                                                unsigned short* __restrict__ Kbf,
                                                unsigned short* __restrict__ Vtg) {
    __shared__ float T[32 * 36];
    if (blockIdx.x < 2048) {
        size_t i = ((size_t)blockIdx.x * 256 + threadIdx.x) * 8;
        *(ushort8*)(Kbf + i) = cvt8(Kg + i);
        return;
    }
    const int bid = blockIdx.x - 2048;
    const int b  = bid >> 9;
    const int kt = (bid >> 2) & 127;
    const int dt = bid & 3;
    const int tid = threadIdx.x;
    {
        int r = tid >> 3, c4 = (tid & 7) * 4;
        f32x4 v = *(const f32x4*)(Vg + ((size_t)b * SEQ + kt * 32 + r) * DH + dt * 32 + c4);
        *(f32x4*)(&T[r * 36 + c4]) = v;
    }
    __syncthreads();
    {
        int rd = tid >> 3, kc4 = (tid & 7) * 4;
        unsigned long long w = 0;
#pragma unroll
        for (int j = 0; j < 4; ++j)
            w |= (unsigned long long)f2bf(T[(kc4 + j) * 36 + rd]) << (16 * j);
        *(unsigned long long*)(Vtg + ((size_t)b * DH + dt * 32 + rd) * SEQ + kt * 32 + kc4) = w;
    }
}

// ---------------- staging ----------------
// PREP path: 8 x global_load_lds per wave per step (4 K-chunks + 4 V-chunks, 1KB each).
// Swizzles live in the per-lane SOURCE address; LDS dest stays linear (gll requirement).
__device__ __forceinline__ void issue_stage(const unsigned short* __restrict__ Kbf,
                                            const unsigned short* __restrict__ Vtg,
                                            unsigned short* sm16, int b, int kh, int qh,
                                            int lane, int t)
{
    const int buf = t & 1;
    const int kb  = kh * 2048 + t * 32;
    const int rin = lane >> 4;             // 0..3
    const int sb  = (lane & 15) << 4;      // byte col within row, 16B granular
    const unsigned short* Kb = Kbf + (size_t)b * SEQ * DH;
#pragma unroll
    for (int ch = 0; ch < 4; ++ch) {
        const int row = qh * 16 + ch * 4 + rin;
        const unsigned char* src =
            (const unsigned char*)(Kb + (size_t)(kb + row) * DH) + (sb ^ ((row & 7) << 4));
        unsigned short* dst = sm16 + (kh * 2 + buf) * 4096 + (qh * 16 + ch * 4) * 128;
        gll16(src, dst);
    }
    const unsigned short* Vb = Vtg + (size_t)b * DH * SEQ;
    const int vr = lane >> 2, vs = lane & 3;
#pragma unroll
    for (int ch = 0; ch < 4; ++ch) {
        const int row = qh * 64 + ch * 16 + vr;
        const int slot = vs ^ ((row >> 1) & 3);          // V source-side swizzle
        const unsigned short* src = Vb + (size_t)row * SEQ + kb + slot * 8;
        unsigned short* dst = sm16 + OFF_V + (kh * 2 + buf) * 4096 + (qh * 64 + ch * 16) * 32;
        gll16(src, dst);
    }
}

// fallback (ws too small): fp32 loads + cvt, ds_write to the SAME layouts. Correctness only.
__device__ __forceinline__ void stage_fallback(const float* __restrict__ Kg,
                                               const float* __restrict__ Vg,
                                               unsigned short* sm16, int b, int tid, int t)
{
    const int buf = t & 1;
#pragma unroll
    for (int s = 0; s < 2; ++s) {
        const int kb = s * 2048 + t * 32;
        {   // K: 32 rows x 128 u16, swizzled
            int r = tid >> 3, cg = tid & 7;
            const float* sp = Kg + ((size_t)b * SEQ + kb + r) * DH + cg * 16;
            ushort8 lo = cvt8(sp), hi = cvt8(sp + 8);
            unsigned char* kd = (unsigned char*)(sm16 + (s * 2 + buf) * 4096) + r * 256;
            int sbb = cg * 32, m = (r & 7) << 4;
            *(ushort8*)(kd + (sbb ^ m))        = lo;
            *(ushort8*)(kd + ((sbb + 16) ^ m)) = hi;
        }
        {   // V^T: 128 d-rows x 32 keys, slot-swizzled to match PREP layout
            int d = tid >> 1, half = tid & 1, sw = (d >> 1) & 3;
            ushort8 a, c;
#pragma unroll
            for (int j = 0; j < 8; ++j) {
                a[j] = f2bf(Vg[((size_t)b * SEQ + kb + half * 16 + j) * DH + d]);
                c[j] = f2bf(Vg[((size_t)b * SEQ + kb + half * 16 + 8 + j) * DH + d]);
            }
            unsigned short* vd = sm16 + OFF_V + (s * 2 + buf) * 4096 + d * 32;
            *(ushort8*)(vd + ((half * 2    ) ^ sw) * 8) = a;
            *(ushort8*)(vd + ((half * 2 + 1) ^ sw) * 8) = c;
        }
    }
}

// ---------------- main attention ----------------
template<int TR, int PREP>
__device__ __forceinline__ void attn_body(
    const float* __restrict__ Qg, const float* __restrict__ Kg,
    const float* __restrict__ Vg,
    const unsigned short* __restrict__ Kbf, const unsigned short* __restrict__ Vtg,
    float* __restrict__ Og, unsigned short* sm16, int b, int qt5)
{
    const int tid  = threadIdx.x;
    const int wv   = tid >> 6;
    const int lane = tid & 63;
    const int l16  = lane & 15;
    const int quad = lane >> 4;
    const int qh = wv & 1;        // q-half of the block (32 q each)
    const int kh = wv >> 1;       // key-half stream (2048 keys each)

    const size_t qbase = (size_t)b * SEQ + (size_t)qt5 * 64 + qh * 32;

    // Q fragments: A[m=q=l16][k=quad*8+j], 2 q-subtiles x 4 d-chunks
    bf16x8 qf[2][4];
#pragma unroll
    for (int qt = 0; qt < 2; ++qt) {
        const float* qp = Qg + (qbase + qt * 16 + l16) * DH + quad * 8;
#pragma unroll
        for (int c = 0; c < 4; ++c)
            qf[qt][c] = __builtin_bit_cast(bf16x8, cvt8(qp + c * 32));
    }

    const f32x4 vzero = {0.f, 0.f, 0.f, 0.f};
    f32x4 oacc[2][8];
#pragma unroll
    for (int qt = 0; qt < 2; ++qt)
#pragma unroll
        for (int c = 0; c < 8; ++c) oacc[qt][c] = vzero;
    float lp[2][4] = {{0.f,0.f,0.f,0.f},{0.f,0.f,0.f,0.f}};

    unsigned short* Pw = sm16 + OFF_P + wv * 1280;
    const int swzm = (l16 & 7) << 4;        // K read-side XOR (byte units)
    const int vsw  = ((l16 >> 1) & 3) << 3; // V read-side XOR base (u16 units): slot^((d>>1)&3)
    const int voff = (quad << 3) ^ vsw;     // lane-constant V read offset within row

    // drain Q loads so the counted-vmcnt discipline below starts clean
    asm volatile("s_waitcnt vmcnt(0)" ::: "memory");

    // prologue: stage tile 0 into buf 0
    if (PREP) issue_stage(Kbf, Vtg, sm16, b, kh, qh, lane, 0);
    else      stage_fallback(Kg, Vg, sm16, b, tid, 0);

    for (int t = 0; t < 64; ++t) {
        __builtin_amdgcn_s_barrier();          // B1: all compute(t-1) tile reads done
        asm volatile("" ::: "memory");
        if (PREP) {
            if (t < 63) {
                issue_stage(Kbf, Vtg, sm16, b, kh, qh, lane, t + 1);
                // 8 newest (tile t+1) stay in flight across the barrier; tile t drained
                asm volatile("s_waitcnt vmcnt(8)" ::: "memory");
            } else {
                asm volatile("s_waitcnt vmcnt(0)" ::: "memory");
            }
        } else {
            if (t < 63) stage_fallback(Kg, Vg, sm16, b, tid, t + 1);
            asm volatile("s_waitcnt vmcnt(0) lgkmcnt(0)" ::: "memory");
        }
        __builtin_amdgcn_s_barrier();          // B2: tile t visible to all waves
        asm volatile("" ::: "memory");

        const unsigned char*  Kbb = (const unsigned char*)(sm16 + (kh * 2 + (t & 1)) * 4096);
        const unsigned short* Vt  = sm16 + OFF_V + (kh * 2 + (t & 1)) * 4096;

        // ---- S = Q*K^T (32q x 32key): B-frags shared across q-subtiles
        __builtin_amdgcn_s_setprio(1);
        f32x4 s[2][2] = {{vzero, vzero}, {vzero, vzero}};
#pragma unroll
        for (int c = 0; c < 4; ++c) {
            bf16x8 k0 = ldb((const unsigned short*)(Kbb + l16 * 256        + ((c * 64 + quad * 16) ^ swzm)));
            bf16x8 k1 = ldb((const unsigned short*)(Kbb + (16 + l16) * 256 + ((c * 64 + quad * 16) ^ swzm)));
#pragma unroll
            for (int qt = 0; qt < 2; ++qt) {
                s[qt][0] = __builtin_amdgcn_mfma_f32_16x16x32_bf16(qf[qt][c], k0, s[qt][0], 0, 0, 0);
                s[qt][1] = __builtin_amdgcn_mfma_f32_16x16x32_bf16(qf[qt][c], k1, s[qt][1], 0, 0, 0);
            }
        }
        __builtin_amdgcn_s_setprio(0);

        // ---- P = exp2(S*SC); write per-wave P [q 0..31][key 0..31]
#pragma unroll
        for (int qt = 0; qt < 2; ++qt)
#pragma unroll
            for (int ks = 0; ks < 2; ++ks)
#pragma unroll
                for (int r = 0; r < 4; ++r) {
                    float p = exp2f(s[qt][ks][r] * SC);
                    if (TR == 0) {
                        lp[qt][r] += p;
                        Pw[(qt * 16 + quad * 4 + r) * PSTR + ks * 16 + l16] = f2bf(p);
                    } else {
                        lp[qt][0] += p;
                        Pw[(qt * 16 + l16) * PSTR + ks * 16 + quad * 4 + r] = f2bf(p);
                    }
                }
        asm volatile("s_waitcnt lgkmcnt(0)" ::: "memory");   // wave-local P fence

        // ---- O += P*V : A = P[q][k=quad*8+j], B = V^T[d][key]
        bf16x8 pf0 = ldb(Pw + (l16     ) * PSTR + quad * 8);
        bf16x8 pf1 = ldb(Pw + (16 + l16) * PSTR + quad * 8);
        __builtin_amdgcn_s_setprio(1);
#pragma unroll
        for (int c = 0; c < 8; ++c) {
            int d = c * 16 + l16;
            bf16x8 vf = ldb(Vt + d * 32 + voff);
            oacc[0][c] = __builtin_amdgcn_mfma_f32_16x16x32_bf16(pf0, vf, oacc[0][c], 0, 0, 0);
            oacc[1][c] = __builtin_amdgcn_mfma_f32_16x16x32_bf16(pf1, vf, oacc[1][c], 0, 0, 0);
        }
        __builtin_amdgcn_s_setprio(0);
    }

    // ---- key-half merge: kh=1 dumps numerator+l, kh=0 combines & stores
    float* Om   = (float*)sm16;
    float* lbuf = (float*)((char*)sm16 + LBUF_BYTE);
    __syncthreads();
    if (kh == 1) {
        if (TR == 0) {
#pragma unroll
            for (int qt = 0; qt < 2; ++qt)
#pragma unroll
                for (int c = 0; c < 8; ++c)
                    *(f32x4*)&Om[qh * 4608 + (c * 16 + l16) * 36 + qt * 16 + quad * 4] = oacc[qt][c];
#pragma unroll
            for (int qt = 0; qt < 2; ++qt)
#pragma unroll
                for (int r = 0; r < 4; ++r) {
                    float L = lp[qt][r];
                    L += __shfl_xor(L, 1); L += __shfl_xor(L, 2);
                    L += __shfl_xor(L, 4); L += __shfl_xor(L, 8);
                    if (l16 == 0) lbuf[qh * 32 + qt * 16 + quad * 4 + r] = L;
                }
        } else {
#pragma unroll
            for (int qt = 0; qt < 2; ++qt)
#pragma unroll
                for (int c = 0; c < 8; ++c)
                    *(f32x4*)&Om[qh * 4224 + (qt * 16 + l16) * 132 + c * 16 + quad * 4] = oacc[qt][c];
#pragma unroll
            for (int qt = 0; qt < 2; ++qt) {
                float L = lp[qt][0];
                L += __shfl_xor(L, 16); L += __shfl_xor(L, 32);
                if (quad == 0) lbuf[qh * 32 + qt * 16 + l16] = L;
            }
        }
    }
    __syncthreads();
    if (kh == 0) {
        if (TR == 0) {
            float Lt[2][4];
#pragma unroll
            for (int qt = 0; qt < 2; ++qt)
#pragma unroll
                for (int r = 0; r < 4; ++r) {
                    float L = lp[qt][r];
                    L += __shfl_xor(L, 1); L += __shfl_xor(L, 2);
                    L += __shfl_xor(L, 4); L += __shfl_xor(L, 8);
                    Lt[qt][r] = 1.0f / (L + lbuf[qh * 32 + qt * 16 + quad * 4 + r]);
                }
#pragma unroll
            for (int qt = 0; qt < 2; ++qt)
#pragma unroll
                for (int c = 0; c < 8; ++c) {
                    f32x4 m = *(f32x4*)&Om[qh * 4608 + (c * 16 + l16) * 36 + qt * 16 + quad * 4];
#pragma unroll
                    for (int r = 0; r < 4; ++r)
                        Og[(qbase + qt * 16 + quad * 4 + r) * DH + c * 16 + l16] =
                            (oacc[qt][c][r] + m[r]) * Lt[qt][r];
                }
        } else {
#pragma unroll
            for (int qt = 0; qt < 2; ++qt) {
                float L = lp[qt][0];
                L += __shfl_xor(L, 16); L += __shfl_xor(L, 32);
                float inv = 1.0f / (L + lbuf[qh * 32 + qt * 16 + l16]);
#pragma unroll
                for (int c = 0; c < 8; ++c) {
                    f32x4 m = *(f32x4*)&Om[qh * 4224 + (qt * 16 + l16) * 132 + c * 16 + quad * 4];
                    f32x4 o;
#pragma unroll
                    for (int r = 0; r < 4; ++r) o[r] = (oacc[qt][c][r] + m[r]) * inv;
                    *(f32x4*)&Og[(qbase + qt * 16 + l16) * DH + c * 16 + quad * 4] = o;
                }
            }
        }
    }
}

__global__ __launch_bounds__(256, 2)
void attn_fwd(const float* __restrict__ Qg, const float* __restrict__ Kg,
              const float* __restrict__ Vg,
              const unsigned short* __restrict__ Kbf,
              const unsigned short* __restrict__ Vtg,
              float* __restrict__ Og, int prep)
{
    extern __shared__ __align__(16) unsigned char smem[];
    unsigned short* sm16 = (unsigned short*)smem;

    const int lane = threadIdx.x & 63;
    const int l16  = lane & 15;

    // orientation probe: A[m][k]=m, B=1/32 -> D[m][n]=m. lane21 reg0: 4.0 vs 5.0
    ushort8 pa, pb;
    unsigned short mv = f2bf((float)l16), ov = f2bf(0.03125f);
#pragma unroll
    for (int j = 0; j < 8; ++j) { pa[j] = mv; pb[j] = ov; }
    f32x4 pz = {0.f, 0.f, 0.f, 0.f};
    f32x4 pd = __builtin_amdgcn_mfma_f32_16x16x32_bf16(
        __builtin_bit_cast(bf16x8, pa), __builtin_bit_cast(bf16x8, pb), pz, 0, 0, 0);
    const bool tr = (__shfl(pd[0], 21) > 4.5f);

    const int b   = blockIdx.x & 7;     // batch == XCD slot (L2 locality)
    const int qt5 = blockIdx.x >> 3;    // 0..63 (64 q-rows each)

    if (prep) {
        if (!tr) attn_body<0,1>(Qg, Kg, Vg, Kbf, Vtg, Og, sm16, b, qt5);
        else     attn_body<1,1>(Qg, Kg, Vg, Kbf, Vtg, Og, sm16, b, qt5);
    } else {
        if (!tr) attn_body<0,0>(Qg, Kg, Vg, Kbf, Vtg, Og, sm16, b, qt5);
        else     attn_body<1,0>(Qg, Kg, Vg, Kbf, Vtg, Og, sm16, b, qt5);
    }
}

extern "C" void kernel_launch(void* const* d_in, const int* in_sizes, int n_in,
                              void* d_out, int out_size, void* d_ws, size_t ws_size,
                              hipStream_t stream) {
    const float* Q = (const float*)d_in[0];
    const float* K = (const float*)d_in[1];
    const float* V = (const float*)d_in[2];
    float* O = (float*)d_out;

    const size_t nelem = (size_t)BATCH * SEQ * DH;        // 4,194,304
    const bool prep = (ws_size >= nelem * 2 * 2);          // 16.8 MB for Kbf + Vtg
    unsigned short* Kbf = (unsigned short*)d_ws;
    unsigned short* Vtg = Kbf + nelem;

    static int smem_cfged = 0;
    if (!smem_cfged) {
        (void)hipFuncSetAttribute((const void*)attn_fwd,
                                  hipFuncAttributeMaxDynamicSharedMemorySize, SMEM_BYTES);
        smem_cfged = 1;
    }

    if (prep)
        prep_all<<<dim3(2048 + BATCH * 128 * 4), 256, 0, stream>>>(K, V, Kbf, Vtg);
    attn_fwd<<<dim3(BATCH * (SEQ / 64)), 256, SMEM_BYTES, stream>>>(Q, K, V, Kbf, Vtg, O, prep ? 1 : 0);
}

// Round 3
// 193.284 us; speedup vs baseline: 1.0309x; 1.0309x over previous
//
#include <hip/hip_runtime.h>

typedef __bf16 bf16x8 __attribute__((ext_vector_type(8)));
typedef float f32x4 __attribute__((ext_vector_type(4)));
typedef float f32x16 __attribute__((ext_vector_type(16)));
typedef unsigned short ushort8 __attribute__((ext_vector_type(8)));
typedef unsigned int uint4v __attribute__((ext_vector_type(4)));

#define BATCH 8
#define SEQ 4096
#define DH 128
#define PSTR 40
#define SC (0.08838834764831845f * 1.4426950408889634f)

// Dynamic-LDS map (u16 units):
//   K tiles : (kh*2+buf)*4096          [0     .. 16383]  32 rows x 128 u16, XOR-swizzled (byte ^= (row&7)<<4)
//   V tiles : OFF_V + (kh*2+buf)*4096  [16384 .. 32767]  128 d-rows x 32 u16; 16B slots XOR-swizzled by (row>>1)&3
//   P       : OFF_P + wv*1280          [32768 .. 37887]  (16x16 fallback path only; body32 uses it for lbuf)
#define OFF_V 16384
#define OFF_P 32768
#define SMEM_BYTES 75776   // 37888 u16 ; x2 blocks/CU = 151.5 KB <= 160 KB
#define LBUF_BYTE 36864    // 16x16 fallback epilogue l-buffer

__device__ __forceinline__ unsigned short f2bf(float x) {
    unsigned int u = __builtin_bit_cast(unsigned int, x);
    u = (u + 0x7FFFu + ((u >> 16) & 1u)) >> 16;
    return (unsigned short)u;
}
__device__ __forceinline__ ushort8 cvt8(const float* __restrict__ p) {
    f32x4 a = *(const f32x4*)p;
    f32x4 b = *(const f32x4*)(p + 4);
    ushort8 r;
    r[0] = f2bf(a[0]); r[1] = f2bf(a[1]); r[2] = f2bf(a[2]); r[3] = f2bf(a[3]);
    r[4] = f2bf(b[0]); r[5] = f2bf(b[1]); r[6] = f2bf(b[2]); r[7] = f2bf(b[3]);
    return r;
}
__device__ __forceinline__ bf16x8 ldb(const unsigned short* p) {
    return __builtin_bit_cast(bf16x8, *(const ushort8*)p);
}
__device__ __forceinline__ void gll16(const void* src, void* dst) {
    // direct global->LDS, 16B per lane; LDS dest = wave-uniform base + lane*16
    __builtin_amdgcn_global_load_lds((const __attribute__((address_space(1))) unsigned int*)src,
                                     (__attribute__((address_space(3))) unsigned int*)dst, 16, 0, 0);
}
__device__ __forceinline__ unsigned int cvtpk(float lo, float hi) {
    unsigned int r;
    asm("v_cvt_pk_bf16_f32 %0, %1, %2" : "=v"(r) : "v"(lo), "v"(hi));
    return r;
}
__device__ __forceinline__ bf16x8 frag4(unsigned int a, unsigned int b,
                                        unsigned int c, unsigned int d) {
    uint4v u; u[0] = a; u[1] = b; u[2] = c; u[3] = d;
    return __builtin_bit_cast(bf16x8, u);
}

// ---------------- merged prep kernel (1 launch): K->bf16, V->bf16 transposed ----------------
__global__ __launch_bounds__(256) void prep_all(const float* __restrict__ Kg,
                                                const float* __restrict__ Vg,
                                                unsigned short* __restrict__ Kbf,
                                                unsigned short* __restrict__ Vtg) {
    __shared__ float T[32 * 36];
    if (blockIdx.x < 2048) {
        size_t i = ((size_t)blockIdx.x * 256 + threadIdx.x) * 8;
        *(ushort8*)(Kbf + i) = cvt8(Kg + i);
        return;
    }
    const int bid = blockIdx.x - 2048;
    const int b  = bid >> 9;
    const int kt = (bid >> 2) & 127;
    const int dt = bid & 3;
    const int tid = threadIdx.x;
    {
        int r = tid >> 3, c4 = (tid & 7) * 4;
        f32x4 v = *(const f32x4*)(Vg + ((size_t)b * SEQ + kt * 32 + r) * DH + dt * 32 + c4);
        *(f32x4*)(&T[r * 36 + c4]) = v;
    }
    __syncthreads();
    {
        int rd = tid >> 3, kc4 = (tid & 7) * 4;
        unsigned long long w = 0;
#pragma unroll
        for (int j = 0; j < 4; ++j)
            w |= (unsigned long long)f2bf(T[(kc4 + j) * 36 + rd]) << (16 * j);
        *(unsigned long long*)(Vtg + ((size_t)b * DH + dt * 32 + rd) * SEQ + kt * 32 + kc4) = w;
    }
}

// ---------------- staging ----------------
// PREP path: 8 x global_load_lds per wave per step (4 K-chunks + 4 V-chunks, 1KB each).
// Swizzles live in the per-lane SOURCE address; LDS dest stays linear (gll requirement).
__device__ __forceinline__ void issue_stage(const unsigned short* __restrict__ Kbf,
                                            const unsigned short* __restrict__ Vtg,
                                            unsigned short* sm16, int b, int kh, int qh,
                                            int lane, int t)
{
    const int buf = t & 1;
    const int kb  = kh * 2048 + t * 32;
    const int rin = lane >> 4;             // 0..3
    const int sb  = (lane & 15) << 4;      // byte col within row, 16B granular
    const unsigned short* Kb = Kbf + (size_t)b * SEQ * DH;
#pragma unroll
    for (int ch = 0; ch < 4; ++ch) {
        const int row = qh * 16 + ch * 4 + rin;
        const unsigned char* src =
            (const unsigned char*)(Kb + (size_t)(kb + row) * DH) + (sb ^ ((row & 7) << 4));
        unsigned short* dst = sm16 + (kh * 2 + buf) * 4096 + (qh * 16 + ch * 4) * 128;
        gll16(src, dst);
    }
    const unsigned short* Vb = Vtg + (size_t)b * DH * SEQ;
    const int vr = lane >> 2, vs = lane & 3;
#pragma unroll
    for (int ch = 0; ch < 4; ++ch) {
        const int row = qh * 64 + ch * 16 + vr;
        const int slot = vs ^ ((row >> 1) & 3);          // V source-side swizzle
        const unsigned short* src = Vb + (size_t)row * SEQ + kb + slot * 8;
        unsigned short* dst = sm16 + OFF_V + (kh * 2 + buf) * 4096 + (qh * 64 + ch * 16) * 32;
        gll16(src, dst);
    }
}

// fallback (ws too small): fp32 loads + cvt, ds_write to the SAME layouts. Correctness only.
__device__ __forceinline__ void stage_fallback(const float* __restrict__ Kg,
                                               const float* __restrict__ Vg,
                                               unsigned short* sm16, int b, int tid, int t)
{
    const int buf = t & 1;
#pragma unroll
    for (int s = 0; s < 2; ++s) {
        const int kb = s * 2048 + t * 32;
        {   // K: 32 rows x 128 u16, swizzled
            int r = tid >> 3, cg = tid & 7;
            const float* sp = Kg + ((size_t)b * SEQ + kb + r) * DH + cg * 16;
            ushort8 lo = cvt8(sp), hi = cvt8(sp + 8);
            unsigned char* kd = (unsigned char*)(sm16 + (s * 2 + buf) * 4096) + r * 256;
            int sbb = cg * 32, m = (r & 7) << 4;
            *(ushort8*)(kd + (sbb ^ m))        = lo;
            *(ushort8*)(kd + ((sbb + 16) ^ m)) = hi;
        }
        {   // V^T: 128 d-rows x 32 keys, slot-swizzled to match PREP layout
            int d = tid >> 1, half = tid & 1, sw = (d >> 1) & 3;
            ushort8 a, c;
#pragma unroll
            for (int j = 0; j < 8; ++j) {
                a[j] = f2bf(Vg[((size_t)b * SEQ + kb + half * 16 + j) * DH + d]);
                c[j] = f2bf(Vg[((size_t)b * SEQ + kb + half * 16 + 8 + j) * DH + d]);
            }
            unsigned short* vd = sm16 + OFF_V + (s * 2 + buf) * 4096 + d * 32;
            *(ushort8*)(vd + ((half * 2    ) ^ sw) * 8) = a;
            *(ushort8*)(vd + ((half * 2 + 1) ^ sw) * 8) = c;
        }
    }
}

// ---------------- main attention, 32x32 swapped-QK^T / in-register-P body ----------------
// S = mfma(K,Q): D[key][q], col=lane&31 = q  -> lane-local softmax row.
// P packed via v_cvt_pk_bf16_f32, half-swapped via shfl_xor(32) into PV A-fragments.
template<int PREP>
__device__ __forceinline__ void attn_body32(
    const float* __restrict__ Qg, const float* __restrict__ Kg,
    const float* __restrict__ Vg,
    const unsigned short* __restrict__ Kbf, const unsigned short* __restrict__ Vtg,
    float* __restrict__ Og, unsigned short* sm16, int b, int qt5)
{
    const int tid  = threadIdx.x;
    const int wv   = tid >> 6;
    const int lane = tid & 63;
    const int l32  = lane & 31;
    const int h    = lane >> 5;
    const int qh = wv & 1;        // q-half of the block (32 q each)
    const int kh = wv >> 1;       // key-half stream (2048 keys each)

    const size_t qbase = (size_t)b * SEQ + (size_t)qt5 * 64 + qh * 32;

    // Q as B-operand: B[k][n=q], n=lane&31 -> row qbase+l32 ; k = h*8+j over d-chunk c
    bf16x8 qf[8];
#pragma unroll
    for (int c = 0; c < 8; ++c)
        qf[c] = __builtin_bit_cast(bf16x8, cvt8(Qg + (qbase + l32) * DH + c * 16 + h * 8));

    f32x16 oacc[4];
#pragma unroll
    for (int dt = 0; dt < 4; ++dt)
#pragma unroll
        for (int r = 0; r < 16; ++r) oacc[dt][r] = 0.f;
    float lpA = 0.f, lpB = 0.f;

    const int swzK = (l32 & 7) << 4;

    asm volatile("s_waitcnt vmcnt(0)" ::: "memory");
    if (PREP) issue_stage(Kbf, Vtg, sm16, b, kh, qh, lane, 0);
    else      stage_fallback(Kg, Vg, sm16, b, tid, 0);

    for (int t = 0; t < 64; ++t) {
        __builtin_amdgcn_s_barrier();          // B1: all compute(t-1) tile reads done
        asm volatile("" ::: "memory");
        if (PREP) {
            if (t < 63) {
                issue_stage(Kbf, Vtg, sm16, b, kh, qh, lane, t + 1);
                asm volatile("s_waitcnt vmcnt(8)" ::: "memory");   // tile t drained, t+1 in flight
            } else {
                asm volatile("s_waitcnt vmcnt(0)" ::: "memory");
            }
        } else {
            if (t < 63) stage_fallback(Kg, Vg, sm16, b, tid, t + 1);
            asm volatile("s_waitcnt vmcnt(0) lgkmcnt(0)" ::: "memory");
        }
        __builtin_amdgcn_s_barrier();          // B2: tile t visible to all waves
        asm volatile("" ::: "memory");

        const unsigned char*  Kbb = (const unsigned char*)(sm16 + (kh * 2 + (t & 1)) * 4096);
        const unsigned short* Vt  = sm16 + OFF_V + (kh * 2 + (t & 1)) * 4096;

        // ---- S^T = K * Q^T : A=K[key=l32][k=c*16+h*8+j], B=Q ; acc 32x32
        __builtin_amdgcn_s_setprio(1);
        f32x16 s;
#pragma unroll
        for (int r = 0; r < 16; ++r) s[r] = 0.f;
#pragma unroll
        for (int c = 0; c < 8; ++c) {
            bf16x8 kf = ldb((const unsigned short*)(Kbb + l32 * 256 + ((c * 32 + h * 16) ^ swzK)));
            s = __builtin_amdgcn_mfma_f32_32x32x16_bf16(kf, qf[c], s, 0, 0, 0);
        }
        __builtin_amdgcn_s_setprio(0);

        // ---- P = exp2(S*SC) in-register; pack to bf16 pairs (keys (K,K+1) per word)
        // word i: keys 8*(i>>1) + 4h + 2*(i&1) .. +1
        unsigned int w[8];
#pragma unroll
        for (int i = 0; i < 8; ++i) {
            float pa = exp2f(s[2 * i]     * SC);
            float pb = exp2f(s[2 * i + 1] * SC);
            lpA += pa; lpB += pb;
            w[i] = cvtpk(pa, pb);
        }
        // half-swap: partner words via one shfl each (payload pre-selected by h)
        unsigned int t0 = __shfl_xor(h ? w[0] : w[2], 32);   // h=0: keys(4,5)   h=1: keys(8,9)
        unsigned int t1 = __shfl_xor(h ? w[1] : w[3], 32);   // h=0: keys(6,7)   h=1: keys(10,11)
        unsigned int t2 = __shfl_xor(h ? w[4] : w[6], 32);   // h=0: keys(20,21) h=1: keys(24,25)
        unsigned int t3 = __shfl_xor(h ? w[5] : w[7], 32);   // h=0: keys(22,23) h=1: keys(26,27)
        // A-frag kc0 = keys 8h..8h+7 ; kc1 = keys 16+8h..+7
        bf16x8 pf0 = frag4(h ? t0 : w[0], h ? t1 : w[1], h ? w[2] : t0, h ? w[3] : t1);
        bf16x8 pf1 = frag4(h ? t2 : w[4], h ? t3 : w[5], h ? w[6] : t2, h ? w[7] : t3);

        // ---- O += P*V : B = V^T[d=dt*32+l32][key kc*16+8h..], slot-swizzled
        __builtin_amdgcn_s_setprio(1);
#pragma unroll
        for (int dt = 0; dt < 4; ++dt) {
            const int d  = dt * 32 + l32;
            const int sw = (d >> 1) & 3;
            bf16x8 v0 = ldb(Vt + d * 32 + ((h    ) ^ sw) * 8);
            bf16x8 v1 = ldb(Vt + d * 32 + ((2 + h) ^ sw) * 8);
            oacc[dt] = __builtin_amdgcn_mfma_f32_32x32x16_bf16(pf0, v0, oacc[dt], 0, 0, 0);
            oacc[dt] = __builtin_amdgcn_mfma_f32_32x32x16_bf16(pf1, v1, oacc[dt], 0, 0, 0);
        }
        __builtin_amdgcn_s_setprio(0);
    }

    // ---- key-half merge. oacc row r -> q = (r&3)+8*(r>>2)+4h ; col = d = dt*32+l32
    float lp2 = lpA + lpB;
    lp2 += __shfl_xor(lp2, 32);          // full 2048-key denominator for q=l32
    float* Om = (float*)sm16;            // 64q x 128d f32 = 32KB (reuses K region)
    float* lb = (float*)((char*)sm16 + 2 * OFF_P);   // 128 floats in old P region
    __syncthreads();
    if (h == 0) lb[kh * 64 + qh * 32 + l32] = lp2;
    if (kh == 1) {
#pragma unroll
        for (int dt = 0; dt < 4; ++dt)
#pragma unroll
            for (int r = 0; r < 16; ++r) {
                const int qr = (r & 3) + 8 * (r >> 2) + 4 * h;
                Om[(qh * 32 + qr) * 128 + dt * 32 + l32] = oacc[dt][r];
            }
    }
    __syncthreads();
    if (kh == 0) {
        float invr[16];
#pragma unroll
        for (int r = 0; r < 16; ++r) {
            const int qr = (r & 3) + 8 * (r >> 2) + 4 * h;
            invr[r] = 1.0f / (lb[qh * 32 + qr] + lb[64 + qh * 32 + qr]);
        }
#pragma unroll
        for (int dt = 0; dt < 4; ++dt)
#pragma unroll
            for (int r = 0; r < 16; ++r) {
                const int qr = (r & 3) + 8 * (r >> 2) + 4 * h;
                Og[(qbase + qr) * DH + dt * 32 + l32] =
                    (oacc[dt][r] + Om[(qh * 32 + qr) * 128 + dt * 32 + l32]) * invr[r];
            }
    }
}

// ---------------- 16x16 fallback body (unchanged, used if 32x32 probe is anomalous) ----------------
template<int TR, int PREP>
__device__ __forceinline__ void attn_body(
    const float* __restrict__ Qg, const float* __restrict__ Kg,
    const float* __restrict__ Vg,
    const unsigned short* __restrict__ Kbf, const unsigned short* __restrict__ Vtg,
    float* __restrict__ Og, unsigned short* sm16, int b, int qt5)
{
    const int tid  = threadIdx.x;
    const int wv   = tid >> 6;
    const int lane = tid & 63;
    const int l16  = lane & 15;
    const int quad = lane >> 4;
    const int qh = wv & 1;
    const int kh = wv >> 1;

    const size_t qbase = (size_t)b * SEQ + (size_t)qt5 * 64 + qh * 32;

    bf16x8 qf[2][4];
#pragma unroll
    for (int qt = 0; qt < 2; ++qt) {
        const float* qp = Qg + (qbase + qt * 16 + l16) * DH + quad * 8;
#pragma unroll
        for (int c = 0; c < 4; ++c)
            qf[qt][c] = __builtin_bit_cast(bf16x8, cvt8(qp + c * 32));
    }

    const f32x4 vzero = {0.f, 0.f, 0.f, 0.f};
    f32x4 oacc[2][8];
#pragma unroll
    for (int qt = 0; qt < 2; ++qt)
#pragma unroll
        for (int c = 0; c < 8; ++c) oacc[qt][c] = vzero;
    float lp[2][4] = {{0.f,0.f,0.f,0.f},{0.f,0.f,0.f,0.f}};

    unsigned short* Pw = sm16 + OFF_P + wv * 1280;
    const int swzm = (l16 & 7) << 4;
    const int vsw  = ((l16 >> 1) & 3) << 3;
    const int voff = (quad << 3) ^ vsw;

    asm volatile("s_waitcnt vmcnt(0)" ::: "memory");
    if (PREP) issue_stage(Kbf, Vtg, sm16, b, kh, qh, lane, 0);
    else      stage_fallback(Kg, Vg, sm16, b, tid, 0);

    for (int t = 0; t < 64; ++t) {
        __builtin_amdgcn_s_barrier();
        asm volatile("" ::: "memory");
        if (PREP) {
            if (t < 63) {
                issue_stage(Kbf, Vtg, sm16, b, kh, qh, lane, t + 1);
                asm volatile("s_waitcnt vmcnt(8)" ::: "memory");
            } else {
                asm volatile("s_waitcnt vmcnt(0)" ::: "memory");
            }
        } else {
            if (t < 63) stage_fallback(Kg, Vg, sm16, b, tid, t + 1);
            asm volatile("s_waitcnt vmcnt(0) lgkmcnt(0)" ::: "memory");
        }
        __builtin_amdgcn_s_barrier();
        asm volatile("" ::: "memory");

        const unsigned char*  Kbb = (const unsigned char*)(sm16 + (kh * 2 + (t & 1)) * 4096);
        const unsigned short* Vt  = sm16 + OFF_V + (kh * 2 + (t & 1)) * 4096;

        f32x4 s[2][2] = {{vzero, vzero}, {vzero, vzero}};
#pragma unroll
        for (int c = 0; c < 4; ++c) {
            bf16x8 k0 = ldb((const unsigned short*)(Kbb + l16 * 256        + ((c * 64 + quad * 16) ^ swzm)));
            bf16x8 k1 = ldb((const unsigned short*)(Kbb + (16 + l16) * 256 + ((c * 64 + quad * 16) ^ swzm)));
#pragma unroll
            for (int qt = 0; qt < 2; ++qt) {
                s[qt][0] = __builtin_amdgcn_mfma_f32_16x16x32_bf16(qf[qt][c], k0, s[qt][0], 0, 0, 0);
                s[qt][1] = __builtin_amdgcn_mfma_f32_16x16x32_bf16(qf[qt][c], k1, s[qt][1], 0, 0, 0);
            }
        }

#pragma unroll
        for (int qt = 0; qt < 2; ++qt)
#pragma unroll
            for (int ks = 0; ks < 2; ++ks)
#pragma unroll
                for (int r = 0; r < 4; ++r) {
                    float p = exp2f(s[qt][ks][r] * SC);
                    if (TR == 0) {
                        lp[qt][r] += p;
                        Pw[(qt * 16 + quad * 4 + r) * PSTR + ks * 16 + l16] = f2bf(p);
                    } else {
                        lp[qt][0] += p;
                        Pw[(qt * 16 + l16) * PSTR + ks * 16 + quad * 4 + r] = f2bf(p);
                    }
                }
        asm volatile("s_waitcnt lgkmcnt(0)" ::: "memory");

        bf16x8 pf0 = ldb(Pw + (l16     ) * PSTR + quad * 8);
        bf16x8 pf1 = ldb(Pw + (16 + l16) * PSTR + quad * 8);
#pragma unroll
        for (int c = 0; c < 8; ++c) {
            int d = c * 16 + l16;
            bf16x8 vf = ldb(Vt + d * 32 + voff);
            oacc[0][c] = __builtin_amdgcn_mfma_f32_16x16x32_bf16(pf0, vf, oacc[0][c], 0, 0, 0);
            oacc[1][c] = __builtin_amdgcn_mfma_f32_16x16x32_bf16(pf1, vf, oacc[1][c], 0, 0, 0);
        }
    }

    float* Om   = (float*)sm16;
    float* lbuf = (float*)((char*)sm16 + LBUF_BYTE);
    __syncthreads();
    if (kh == 1) {
        if (TR == 0) {
#pragma unroll
            for (int qt = 0; qt < 2; ++qt)
#pragma unroll
                for (int c = 0; c < 8; ++c)
                    *(f32x4*)&Om[qh * 4608 + (c * 16 + l16) * 36 + qt * 16 + quad * 4] = oacc[qt][c];
#pragma unroll
            for (int qt = 0; qt < 2; ++qt)
#pragma unroll
                for (int r = 0; r < 4; ++r) {
                    float L = lp[qt][r];
                    L += __shfl_xor(L, 1); L += __shfl_xor(L, 2);
                    L += __shfl_xor(L, 4); L += __shfl_xor(L, 8);
                    if (l16 == 0) lbuf[qh * 32 + qt * 16 + quad * 4 + r] = L;
                }
        } else {
#pragma unroll
            for (int qt = 0; qt < 2; ++qt)
#pragma unroll
                for (int c = 0; c < 8; ++c)
                    *(f32x4*)&Om[qh * 4224 + (qt * 16 + l16) * 132 + c * 16 + quad * 4] = oacc[qt][c];
#pragma unroll
            for (int qt = 0; qt < 2; ++qt) {
                float L = lp[qt][0];
                L += __shfl_xor(L, 16); L += __shfl_xor(L, 32);
                if (quad == 0) lbuf[qh * 32 + qt * 16 + l16] = L;
            }
        }
    }
    __syncthreads();
    if (kh == 0) {
        if (TR == 0) {
            float Lt[2][4];
#pragma unroll
            for (int qt = 0; qt < 2; ++qt)
#pragma unroll
                for (int r = 0; r < 4; ++r) {
                    float L = lp[qt][r];
                    L += __shfl_xor(L, 1); L += __shfl_xor(L, 2);
                    L += __shfl_xor(L, 4); L += __shfl_xor(L, 8);
                    Lt[qt][r] = 1.0f / (L + lbuf[qh * 32 + qt * 16 + quad * 4 + r]);
                }
#pragma unroll
            for (int qt = 0; qt < 2; ++qt)
#pragma unroll
                for (int c = 0; c < 8; ++c) {
                    f32x4 m = *(f32x4*)&Om[qh * 4608 + (c * 16 + l16) * 36 + qt * 16 + quad * 4];
#pragma unroll
                    for (int r = 0; r < 4; ++r)
                        Og[(qbase + qt * 16 + quad * 4 + r) * DH + c * 16 + l16] =
                            (oacc[qt][c][r] + m[r]) * Lt[qt][r];
                }
        } else {
#pragma unroll
            for (int qt = 0; qt < 2; ++qt) {
                float L = lp[qt][0];
                L += __shfl_xor(L, 16); L += __shfl_xor(L, 32);
                float inv = 1.0f / (L + lbuf[qh * 32 + qt * 16 + l16]);
#pragma unroll
                for (int c = 0; c < 8; ++c) {
                    f32x4 m = *(f32x4*)&Om[qh * 4224 + (qt * 16 + l16) * 132 + c * 16 + quad * 4];
                    f32x4 o;
#pragma unroll
                    for (int r = 0; r < 4; ++r) o[r] = (oacc[qt][c][r] + m[r]) * inv;
                    *(f32x4*)&Og[(qbase + qt * 16 + l16) * DH + c * 16 + quad * 4] = o;
                }
            }
        }
    }
}

__global__ __launch_bounds__(256, 2)
void attn_fwd(const float* __restrict__ Qg, const float* __restrict__ Kg,
              const float* __restrict__ Vg,
              const unsigned short* __restrict__ Kbf,
              const unsigned short* __restrict__ Vtg,
              float* __restrict__ Og, int prep)
{
    extern __shared__ __align__(16) unsigned char smem[];
    unsigned short* sm16 = (unsigned short*)smem;

    const int lane = threadIdx.x & 63;

    // 32x32 orientation probe: A[m][k]=m, B=1/16 -> D[m][n]=m.
    // Standard C/D (col=lane&31, row=(reg&3)+8*(reg>>2)+4*(lane>>5)): lane37 reg0 -> 4.0.
    // Transposed would give 5.0.
    ushort8 pa, pb;
    unsigned short mv32 = f2bf((float)(lane & 31)), ov32 = f2bf(0.0625f);
#pragma unroll
    for (int j = 0; j < 8; ++j) { pa[j] = mv32; pb[j] = ov32; }
    f32x16 pz16;
#pragma unroll
    for (int r = 0; r < 16; ++r) pz16[r] = 0.f;
    f32x16 pd32 = __builtin_amdgcn_mfma_f32_32x32x16_bf16(
        __builtin_bit_cast(bf16x8, pa), __builtin_bit_cast(bf16x8, pb), pz16, 0, 0, 0);
    const bool std32 = (__shfl(pd32[0], 37) < 4.5f);

    const int b   = blockIdx.x & 7;     // batch == XCD slot (L2 locality)
    const int qt5 = blockIdx.x >> 3;    // 0..63 (64 q-rows each)

    if (std32) {
        if (prep) attn_body32<1>(Qg, Kg, Vg, Kbf, Vtg, Og, sm16, b, qt5);
        else      attn_body32<0>(Qg, Kg, Vg, Kbf, Vtg, Og, sm16, b, qt5);
        return;
    }

    // fallback: 16x16 path with its own orientation probe
    const int l16 = lane & 15;
    unsigned short mv = f2bf((float)l16), ov = f2bf(0.03125f);
#pragma unroll
    for (int j = 0; j < 8; ++j) { pa[j] = mv; pb[j] = ov; }
    f32x4 pz = {0.f, 0.f, 0.f, 0.f};
    f32x4 pd = __builtin_amdgcn_mfma_f32_16x16x32_bf16(
        __builtin_bit_cast(bf16x8, pa), __builtin_bit_cast(bf16x8, pb), pz, 0, 0, 0);
    const bool tr = (__shfl(pd[0], 21) > 4.5f);

    if (prep) {
        if (!tr) attn_body<0,1>(Qg, Kg, Vg, Kbf, Vtg, Og, sm16, b, qt5);
        else     attn_body<1,1>(Qg, Kg, Vg, Kbf, Vtg, Og, sm16, b, qt5);
    } else {
        if (!tr) attn_body<0,0>(Qg, Kg, Vg, Kbf, Vtg, Og, sm16, b, qt5);
        else     attn_body<1,0>(Qg, Kg, Vg, Kbf, Vtg, Og, sm16, b, qt5);
    }
}

extern "C" void kernel_launch(void* const* d_in, const int* in_sizes, int n_in,
                              void* d_out, int out_size, void* d_ws, size_t ws_size,
                              hipStream_t stream) {
    const float* Q = (const float*)d_in[0];
    const float* K = (const float*)d_in[1];
    const float* V = (const float*)d_in[2];
    float* O = (float*)d_out;

    const size_t nelem = (size_t)BATCH * SEQ * DH;        // 4,194,304
    const bool prep = (ws_size >= nelem * 2 * 2);          // 16.8 MB for Kbf + Vtg
    unsigned short* Kbf = (unsigned short*)d_ws;
    unsigned short* Vtg = Kbf + nelem;

    static int smem_cfged = 0;
    if (!smem_cfged) {
        (void)hipFuncSetAttribute((const void*)attn_fwd,
                                  hipFuncAttributeMaxDynamicSharedMemorySize, SMEM_BYTES);
        smem_cfged = 1;
    }

    if (prep)
        prep_all<<<dim3(2048 + BATCH * 128 * 4), 256, 0, stream>>>(K, V, Kbf, Vtg);
    attn_fwd<<<dim3(BATCH * (SEQ / 64)), 256, SMEM_BYTES, stream>>>(Q, K, V, Kbf, Vtg, O, prep ? 1 : 0);
}